// Round 19
// baseline (65.498 us; speedup 1.0000x reference)
//
#include <hip/hip_runtime.h>

#define ROWS 8192
#define KDIM 4096
#define NDIM 4096

typedef float f32x4 __attribute__((ext_vector_type(4)));

// ws layout (floats):
//   w01 : [4096][16]  at 0      (65536)   -- k-major, r2 contiguous
//   w23 : [16][4096]  at 65536  (65536)
//
// R19: wave-specialized pipeline. Block = 512 thr, 16 rows = tiles A,B (8+8).
//   stage 1: all 8 waves P1(A) (K/8 each)          -- pure read
//   stage 2: waves 0-3 P1(B) (K/4 each)  ||  waves 4-7 P2(A)  -- DUPLEX
//   stage 3: all 8 waves P2(B)                      -- pure write
// P1 engine + butterfly and P2 j-sweep byte-identical to R5/R17 verified.

__device__ inline f32x4 fma4(float s, f32x4 w, f32x4 a) {
    a.x = fmaf(s, w.x, a.x);
    a.y = fmaf(s, w.y, a.y);
    a.z = fmaf(s, w.z, a.z);
    a.w = fmaf(s, w.w, a.w);
    return a;
}
__device__ inline f32x4 shfl_xor4(f32x4 v, int m) {
    v.x = __shfl_xor(v.x, m, 64);
    v.y = __shfl_xor(v.y, m, 64);
    v.z = __shfl_xor(v.z, m, 64);
    v.w = __shfl_xor(v.w, m, 64);
    return v;
}

// ---------------------------------------------------------------------------
// Build W01 (4096x16, k-major) and W23 (16x4096) from the TT cores.
// ---------------------------------------------------------------------------
__global__ __launch_bounds__(256) void tt_prep(
    const float* __restrict__ c0, const float* __restrict__ c1,
    const float* __restrict__ c2, const float* __restrict__ c3,
    float* __restrict__ w01, float* __restrict__ w23)
{
    int gid = blockIdx.x * 256 + threadIdx.x;  // 0..131071
    if (gid < 65536) {
        int p = gid >> 4, r2 = gid & 15;
        int n0 = p >> 6, n1 = p & 63;
        float s = 0.f;
        #pragma unroll
        for (int r1 = 0; r1 < 16; ++r1)
            s = fmaf(c0[n0 * 16 + r1], c1[(r1 * 64 + n1) * 16 + r2], s);
        w01[gid] = s;
    } else {
        int g = gid - 65536;
        int r2 = g >> 12, j = g & 4095;
        int n2 = j >> 6, n3 = j & 63;
        float s = 0.f;
        #pragma unroll
        for (int r3 = 0; r3 < 16; ++r3)
            s = fmaf(c2[(r2 * 64 + n2) * 16 + r3], c3[r3 * 64 + n3], s);
        w23[g] = s;
    }
}

// ---------------------------------------------------------------------------
// P1 engine: NIT 64-k iterations starting at xb/wb; returns this lane's
// reduced f32x4 (row=(lane>>3)&7, quad q) via the R5-verified butterfly.
// ---------------------------------------------------------------------------
__device__ __forceinline__ f32x4 p1_engine(
    const float* __restrict__ xb, const float* __restrict__ wb,
    int nit, int lane, int q, int klane)
{
    f32x4 acc[8];
    #pragma unroll
    for (int r = 0; r < 8; ++r) acc[r] = (f32x4)(0.f);

    #pragma unroll 2
    for (int it = 0; it < nit; ++it) {
        const int kk0 = it * 64 + klane * 4;
        f32x4 wq[4];
        #pragma unroll
        for (int kk = 0; kk < 4; ++kk)
            wq[kk] = *(const f32x4*)&wb[(size_t)(kk0 + kk) * 16 + q * 4];
        f32x4 xv[8];
        #pragma unroll
        for (int r = 0; r < 8; ++r)
            xv[r] = *(const f32x4*)&xb[(size_t)r * KDIM + kk0];
        #pragma unroll
        for (int kk = 0; kk < 4; ++kk)
            #pragma unroll
            for (int r = 0; r < 8; ++r)
                acc[r] = fma4(xv[r][kk], wq[kk], acc[r]);
    }

    const bool b5 = lane & 32, b4 = lane & 16, b3 = lane & 8;
    f32x4 s1[4];
    #pragma unroll
    for (int j = 0; j < 4; ++j) {
        f32x4 send = b5 ? acc[j] : acc[4 + j];
        f32x4 keep = b5 ? acc[4 + j] : acc[j];
        s1[j] = keep + shfl_xor4(send, 32);
    }
    f32x4 s2[2];
    #pragma unroll
    for (int j = 0; j < 2; ++j) {
        f32x4 send = b4 ? s1[j] : s1[2 + j];
        f32x4 keep = b4 ? s1[2 + j] : s1[j];
        s2[j] = keep + shfl_xor4(send, 16);
    }
    f32x4 s3;
    {
        f32x4 send = b3 ? s2[0] : s2[1];
        f32x4 keep = b3 ? s2[1] : s2[0];
        s3 = keep + shfl_xor4(send, 8);
    }
    s3 += shfl_xor4(s3, 4);
    return s3;
}

// P2 row-sweep for one j-position: 16 fma4 against ts row, NT store.
__device__ __forceinline__ void p2_rows(
    const float (*ts)[16], const f32x4* w, float* __restrict__ out,
    size_t obase, int j0)
{
    #pragma unroll 2
    for (int row = 0; row < 8; ++row) {
        const f32x4* trp = (const f32x4*)&ts[row][0];
        f32x4 t0 = trp[0], t1 = trp[1], t2 = trp[2], t3 = trp[3];
        f32x4 a = (f32x4)(0.f);
        a = fma4(t0.x, w[0],  a); a = fma4(t0.y, w[1],  a);
        a = fma4(t0.z, w[2],  a); a = fma4(t0.w, w[3],  a);
        a = fma4(t1.x, w[4],  a); a = fma4(t1.y, w[5],  a);
        a = fma4(t1.z, w[6],  a); a = fma4(t1.w, w[7],  a);
        a = fma4(t2.x, w[8],  a); a = fma4(t2.y, w[9],  a);
        a = fma4(t2.z, w[10], a); a = fma4(t2.w, w[11], a);
        a = fma4(t3.x, w[12], a); a = fma4(t3.y, w[13], a);
        a = fma4(t3.z, w[14], a); a = fma4(t3.w, w[15], a);
        __builtin_nontemporal_store(a,
            (f32x4*)&out[obase + (size_t)row * NDIM + j0]);
    }
}

// ---------------------------------------------------------------------------
// Fused pipelined: out[16 rows] per block, grid 512 x 512 thr.
// ---------------------------------------------------------------------------
__global__ __launch_bounds__(512) void tt_fused(
    const float* __restrict__ x, const float* __restrict__ w01,
    const float* __restrict__ w23, float* __restrict__ out)
{
    __shared__ __align__(16) float tsp[8][8][16];
    __shared__ __align__(16) float tsA[8][16];
    __shared__ __align__(16) float tsB[8][16];
    const int t = threadIdx.x;
    const int lane = t & 63;
    const int wv = t >> 6;            // 0..7
    const int q = lane & 3;
    const int klane = lane >> 2;
    const int rowA = blockIdx.x * 16;
    const int rowB = rowA + 8;
    const size_t obaseA = (size_t)rowA * NDIM;
    const size_t obaseB = (size_t)rowB * NDIM;

    // ---- Stage 1: all 8 waves, P1(A), K/8 = 512 per wave (pure read).
    {
        const int k0 = wv * 512;
        f32x4 s3 = p1_engine(x + (size_t)rowA * KDIM + k0,
                             w01 + (size_t)k0 * 16, 8, lane, q, klane);
        if ((lane & 4) == 0) {
            int row = (lane >> 3) & 7;
            *(f32x4*)&tsp[wv][row][q * 4] = s3;
        }
    }
    __syncthreads();
    if (t < 128) {
        int row = t >> 4, r = t & 15;
        tsA[row][r] = tsp[0][row][r] + tsp[1][row][r] + tsp[2][row][r]
                    + tsp[3][row][r] + tsp[4][row][r] + tsp[5][row][r]
                    + tsp[6][row][r] + tsp[7][row][r];
    }
    __syncthreads();

    // ---- Stage 2 (DUPLEX): waves 0-3 P1(B) K/4 each; waves 4-7 P2(A).
    if (wv < 4) {
        const int k0 = wv * 1024;
        f32x4 s3 = p1_engine(x + (size_t)rowB * KDIM + k0,
                             w01 + (size_t)k0 * 16, 16, lane, q, klane);
        if ((lane & 4) == 0) {
            int row = (lane >> 3) & 7;
            *(f32x4*)&tsp[wv][row][q * 4] = s3;
        }
    } else {
        const int t2 = t - 256;       // 0..255
        #pragma unroll 1
        for (int jt = 0; jt < 4; ++jt) {
            const int j0 = jt * 1024 + t2 * 4;
            f32x4 w[16];
            #pragma unroll
            for (int r = 0; r < 16; ++r)
                w[r] = *(const f32x4*)&w23[r * NDIM + j0];
            p2_rows(tsA, w, out, obaseA, j0);
        }
    }
    __syncthreads();
    if (t < 128) {
        int row = t >> 4, r = t & 15;
        tsB[row][r] = tsp[0][row][r] + tsp[1][row][r]
                    + tsp[2][row][r] + tsp[3][row][r];
    }
    __syncthreads();

    // ---- Stage 3: all 512 thr, P2(B), 2 j-passes of 2048 (pure write).
    #pragma unroll 1
    for (int jt = 0; jt < 2; ++jt) {
        const int j0 = jt * 2048 + t * 4;
        f32x4 w[16];
        #pragma unroll
        for (int r = 0; r < 16; ++r)
            w[r] = *(const f32x4*)&w23[r * NDIM + j0];
        p2_rows(tsB, w, out, obaseB, j0);
    }
}

extern "C" void kernel_launch(void* const* d_in, const int* in_sizes, int n_in,
                              void* d_out, int out_size, void* d_ws, size_t ws_size,
                              hipStream_t stream) {
    const float* x  = (const float*)d_in[0];
    const float* c0 = (const float*)d_in[1];
    const float* c1 = (const float*)d_in[2];
    const float* c2 = (const float*)d_in[3];
    const float* c3 = (const float*)d_in[4];
    float* out = (float*)d_out;

    float* w01 = (float*)d_ws;
    float* w23 = w01 + 65536;

    tt_prep<<<512, 256, 0, stream>>>(c0, c1, c2, c3, w01, w23);
    tt_fused<<<512, 512, 0, stream>>>(x, w01, w23, out);
}

// Round 20
// 62.840 us; speedup vs baseline: 1.0423x; 1.0423x over previous
//
#include <hip/hip_runtime.h>

#define ROWS 8192
#define KDIM 4096
#define NDIM 4096

typedef float f32x4 __attribute__((ext_vector_type(4)));

// ws layout (floats):
//   w01 : [4096][16]  at 0      (65536)   -- k-major, r2 contiguous
//   w23 : [16][4096]  at 65536  (65536)
//
// R20: R17 (best, 60.0us) + ONE variable: phase-1 unroll 2 -> 4 with
// __launch_bounds__(256,4) (VGPR cap 128, same 4 waves/SIMD occupancy).
// Doubles outstanding x-loads per wave; tests whether P1's 3.5 TB/s read
// rate is issue-depth-limited. If neutral -> R17 is the roofline keeper.

__device__ inline f32x4 fma4(float s, f32x4 w, f32x4 a) {
    a.x = fmaf(s, w.x, a.x);
    a.y = fmaf(s, w.y, a.y);
    a.z = fmaf(s, w.z, a.z);
    a.w = fmaf(s, w.w, a.w);
    return a;
}
__device__ inline f32x4 shfl_xor4(f32x4 v, int m) {
    v.x = __shfl_xor(v.x, m, 64);
    v.y = __shfl_xor(v.y, m, 64);
    v.z = __shfl_xor(v.z, m, 64);
    v.w = __shfl_xor(v.w, m, 64);
    return v;
}

// ---------------------------------------------------------------------------
// Build W01 (4096x16, k-major) and W23 (16x4096) from the TT cores.
// ---------------------------------------------------------------------------
__global__ __launch_bounds__(256) void tt_prep(
    const float* __restrict__ c0, const float* __restrict__ c1,
    const float* __restrict__ c2, const float* __restrict__ c3,
    float* __restrict__ w01, float* __restrict__ w23)
{
    int gid = blockIdx.x * 256 + threadIdx.x;  // 0..131071
    if (gid < 65536) {
        int p = gid >> 4, r2 = gid & 15;
        int n0 = p >> 6, n1 = p & 63;
        float s = 0.f;
        #pragma unroll
        for (int r1 = 0; r1 < 16; ++r1)
            s = fmaf(c0[n0 * 16 + r1], c1[(r1 * 64 + n1) * 16 + r2], s);
        w01[gid] = s;
    } else {
        int g = gid - 65536;
        int r2 = g >> 12, j = g & 4095;
        int n2 = j >> 6, n3 = j & 63;
        float s = 0.f;
        #pragma unroll
        for (int r3 = 0; r3 < 16; ++r3)
            s = fmaf(c2[(r2 * 64 + n2) * 16 + r3], c3[r3 * 64 + n3], s);
        w23[g] = s;
    }
}

// ---------------------------------------------------------------------------
// Fused: out[8 rows] = (x[8 rows] @ W01) @ W23 per block. Grid 1024.
// ---------------------------------------------------------------------------
__global__ __launch_bounds__(256, 4) void tt_fused(
    const float* __restrict__ x, const float* __restrict__ w01,
    const float* __restrict__ w23, float* __restrict__ out)
{
    __shared__ __align__(16) float tsp[4][8][16];  // per-wave partial T
    __shared__ __align__(16) float ts[8][16];      // summed T tile
    const int t = threadIdx.x;
    const int lane = t & 63;
    const int wv = t >> 6;            // wave 0..3: K segment owner
    const int q = lane & 3;           // r2 quad
    const int klane = lane >> 2;      // 0..15
    const int row0 = blockIdx.x * 8;
    const int k0 = wv * 1024;

    const float* xb = x + (size_t)row0 * KDIM + k0;
    const float* wb = w01 + (size_t)k0 * 16;

    // ---- Phase 1: R5-verified broadcast engine; unroll 4 (R20 variable).
    f32x4 acc[8];
    #pragma unroll
    for (int r = 0; r < 8; ++r) acc[r] = (f32x4)(0.f);

    #pragma unroll 4
    for (int it = 0; it < 1024 / 64; ++it) {
        const int kk0 = it * 64 + klane * 4;
        f32x4 wq[4];
        #pragma unroll
        for (int kk = 0; kk < 4; ++kk)
            wq[kk] = *(const f32x4*)&wb[(size_t)(kk0 + kk) * 16 + q * 4];
        f32x4 xv[8];
        #pragma unroll
        for (int r = 0; r < 8; ++r)
            xv[r] = *(const f32x4*)&xb[(size_t)r * KDIM + kk0];
        #pragma unroll
        for (int kk = 0; kk < 4; ++kk)
            #pragma unroll
            for (int r = 0; r < 8; ++r)
                acc[r] = fma4(xv[r][kk], wq[kk], acc[r]);
    }

    // R5-verified reduce-scatter butterfly over klane (static indices only).
    const bool b5 = lane & 32, b4 = lane & 16, b3 = lane & 8;
    f32x4 s1[4];
    #pragma unroll
    for (int j = 0; j < 4; ++j) {
        f32x4 send = b5 ? acc[j] : acc[4 + j];
        f32x4 keep = b5 ? acc[4 + j] : acc[j];
        s1[j] = keep + shfl_xor4(send, 32);
    }
    f32x4 s2[2];
    #pragma unroll
    for (int j = 0; j < 2; ++j) {
        f32x4 send = b4 ? s1[j] : s1[2 + j];
        f32x4 keep = b4 ? s1[2 + j] : s1[j];
        s2[j] = keep + shfl_xor4(send, 16);
    }
    f32x4 s3;
    {
        f32x4 send = b3 ? s2[0] : s2[1];
        f32x4 keep = b3 ? s2[1] : s2[0];
        s3 = keep + shfl_xor4(send, 8);
    }
    s3 += shfl_xor4(s3, 4);

    if ((lane & 4) == 0) {
        int row = (lane >> 3) & 7;
        *(f32x4*)&tsp[wv][row][q * 4] = s3;
    }
    __syncthreads();

    // Sum the 4 wave partials into ts[8][16].
    if (t < 128) {
        int row = t >> 4, r = t & 15;
        ts[row][r] = tsp[0][row][r] + tsp[1][row][r]
                   + tsp[2][row][r] + tsp[3][row][r];
    }
    __syncthreads();

    // ---- Phase 2: R5-verified j-sweep. 4 j-tiles of 1024; w[16] in regs.
    const size_t obase = (size_t)row0 * NDIM;
    #pragma unroll 1
    for (int jt = 0; jt < 4; ++jt) {
        const int j0 = jt * 1024 + t * 4;
        f32x4 w[16];
        #pragma unroll
        for (int r = 0; r < 16; ++r)
            w[r] = *(const f32x4*)&w23[r * NDIM + j0];
        #pragma unroll 2
        for (int row = 0; row < 8; ++row) {
            const f32x4* trp = (const f32x4*)&ts[row][0];
            f32x4 t0 = trp[0], t1 = trp[1], t2 = trp[2], t3 = trp[3];
            f32x4 a = (f32x4)(0.f);
            a = fma4(t0.x, w[0],  a); a = fma4(t0.y, w[1],  a);
            a = fma4(t0.z, w[2],  a); a = fma4(t0.w, w[3],  a);
            a = fma4(t1.x, w[4],  a); a = fma4(t1.y, w[5],  a);
            a = fma4(t1.z, w[6],  a); a = fma4(t1.w, w[7],  a);
            a = fma4(t2.x, w[8],  a); a = fma4(t2.y, w[9],  a);
            a = fma4(t2.z, w[10], a); a = fma4(t2.w, w[11], a);
            a = fma4(t3.x, w[12], a); a = fma4(t3.y, w[13], a);
            a = fma4(t3.z, w[14], a); a = fma4(t3.w, w[15], a);
            __builtin_nontemporal_store(a,
                (f32x4*)&out[obase + (size_t)row * NDIM + j0]);
        }
    }
}

extern "C" void kernel_launch(void* const* d_in, const int* in_sizes, int n_in,
                              void* d_out, int out_size, void* d_ws, size_t ws_size,
                              hipStream_t stream) {
    const float* x  = (const float*)d_in[0];
    const float* c0 = (const float*)d_in[1];
    const float* c1 = (const float*)d_in[2];
    const float* c2 = (const float*)d_in[3];
    const float* c3 = (const float*)d_in[4];
    float* out = (float*)d_out;

    float* w01 = (float*)d_ws;
    float* w23 = w01 + 65536;

    tt_prep<<<512, 256, 0, stream>>>(c0, c1, c2, c3, w01, w23);
    tt_fused<<<1024, 256, 0, stream>>>(x, w01, w23, out);
}

// Round 21
// 55.958 us; speedup vs baseline: 1.1705x; 1.1230x over previous
//
#include <hip/hip_runtime.h>

#define ROWS 8192
#define KDIM 4096
#define NDIM 4096

typedef float f32x4 __attribute__((ext_vector_type(4)));

// ws layout (floats):
//   w01 : [4096][16]  at 0      (65536)   -- k-major, r2 contiguous
//   w23 : [16][4096]  at 65536  (65536)
//
// R21: R17 fused (best, 60.0us) + ONE variable: phase-1 x comes via
// wave-private LDS staging with PLAIN fully-coalesced loads (1 KB unique
// per instr, 4x fewer x-load instrs, 4x less L1 return traffic); the
// 4-lane-redundant broadcast reads move to LDS where same-address
// broadcast is free. R11 tested this with NT staging loads (the since-
// proven poison); this is the fair test. Everything else R17-identical.

__device__ inline f32x4 fma4(float s, f32x4 w, f32x4 a) {
    a.x = fmaf(s, w.x, a.x);
    a.y = fmaf(s, w.y, a.y);
    a.z = fmaf(s, w.z, a.z);
    a.w = fmaf(s, w.w, a.w);
    return a;
}
__device__ inline f32x4 shfl_xor4(f32x4 v, int m) {
    v.x = __shfl_xor(v.x, m, 64);
    v.y = __shfl_xor(v.y, m, 64);
    v.z = __shfl_xor(v.z, m, 64);
    v.w = __shfl_xor(v.w, m, 64);
    return v;
}

// ---------------------------------------------------------------------------
// Build W01 (4096x16, k-major) and W23 (16x4096) from the TT cores.
// ---------------------------------------------------------------------------
__global__ __launch_bounds__(256) void tt_prep(
    const float* __restrict__ c0, const float* __restrict__ c1,
    const float* __restrict__ c2, const float* __restrict__ c3,
    float* __restrict__ w01, float* __restrict__ w23)
{
    int gid = blockIdx.x * 256 + threadIdx.x;  // 0..131071
    if (gid < 65536) {
        int p = gid >> 4, r2 = gid & 15;
        int n0 = p >> 6, n1 = p & 63;
        float s = 0.f;
        #pragma unroll
        for (int r1 = 0; r1 < 16; ++r1)
            s = fmaf(c0[n0 * 16 + r1], c1[(r1 * 64 + n1) * 16 + r2], s);
        w01[gid] = s;
    } else {
        int g = gid - 65536;
        int r2 = g >> 12, j = g & 4095;
        int n2 = j >> 6, n3 = j & 63;
        float s = 0.f;
        #pragma unroll
        for (int r3 = 0; r3 < 16; ++r3)
            s = fmaf(c2[(r2 * 64 + n2) * 16 + r3], c3[r3 * 64 + n3], s);
        w23[g] = s;
    }
}

// ---------------------------------------------------------------------------
// Fused: out[8 rows] = (x[8 rows] @ W01) @ W23 per block. Grid 1024.
// ---------------------------------------------------------------------------
__global__ __launch_bounds__(256) void tt_fused(
    const float* __restrict__ x, const float* __restrict__ w01,
    const float* __restrict__ w23, float* __restrict__ out)
{
    __shared__ __align__(16) float ldsx[4][8][256]; // 32 KB, wave-private chunks
    __shared__ __align__(16) float tsp[4][8][16];   // per-wave partial T
    __shared__ __align__(16) float ts[8][16];       // summed T tile
    const int t = threadIdx.x;
    const int lane = t & 63;
    const int wv = t >> 6;            // wave 0..3: K segment owner
    const int q = lane & 3;           // r2 quad
    const int klane = lane >> 2;      // 0..15
    const int row0 = blockIdx.x * 8;
    const int k0 = wv * 1024;

    const float* xb = x + (size_t)row0 * KDIM + k0;
    const float* wb = w01 + (size_t)k0 * 16;

    // ---- Phase 1: LDS-staged broadcast engine. 4 chunks of 256 k.
    f32x4 acc[8];
    #pragma unroll
    for (int r = 0; r < 8; ++r) acc[r] = (f32x4)(0.f);

    #pragma unroll 1
    for (int ch = 0; ch < 4; ++ch) {
        // Stage: 8 rows x 256 k, plain fully-coalesced loads (1 KB unique
        // per instruction), then ds_write. Wave-private region: no barrier;
        // compiler inserts the lgkmcnt/vmcnt waits for the RAW/WAR hazards.
        f32x4 xs[8];
        #pragma unroll
        for (int r = 0; r < 8; ++r)
            xs[r] = *(const f32x4*)&xb[(size_t)r * KDIM + ch * 256 + lane * 4];
        #pragma unroll
        for (int r = 0; r < 8; ++r)
            *(f32x4*)&ldsx[wv][r][lane * 4] = xs[r];

        // Compute: 4 x 64-k iterations; x from LDS (4-lane same-address
        // broadcast is free), w from L1/L2 (R5-verified mapping).
        #pragma unroll 2
        for (int it = 0; it < 4; ++it) {
            const int kk0 = it * 64 + klane * 4;
            f32x4 wq[4];
            #pragma unroll
            for (int kk = 0; kk < 4; ++kk)
                wq[kk] = *(const f32x4*)&wb[(size_t)(ch * 256 + kk0 + kk) * 16 + q * 4];
            f32x4 xv[8];
            #pragma unroll
            for (int r = 0; r < 8; ++r)
                xv[r] = *(const f32x4*)&ldsx[wv][r][kk0];
            #pragma unroll
            for (int kk = 0; kk < 4; ++kk)
                #pragma unroll
                for (int r = 0; r < 8; ++r)
                    acc[r] = fma4(xv[r][kk], wq[kk], acc[r]);
        }
    }

    // R5-verified reduce-scatter butterfly over klane (static indices only).
    const bool b5 = lane & 32, b4 = lane & 16, b3 = lane & 8;
    f32x4 s1[4];
    #pragma unroll
    for (int j = 0; j < 4; ++j) {
        f32x4 send = b5 ? acc[j] : acc[4 + j];
        f32x4 keep = b5 ? acc[4 + j] : acc[j];
        s1[j] = keep + shfl_xor4(send, 32);
    }
    f32x4 s2[2];
    #pragma unroll
    for (int j = 0; j < 2; ++j) {
        f32x4 send = b4 ? s1[j] : s1[2 + j];
        f32x4 keep = b4 ? s1[2 + j] : s1[j];
        s2[j] = keep + shfl_xor4(send, 16);
    }
    f32x4 s3;
    {
        f32x4 send = b3 ? s2[0] : s2[1];
        f32x4 keep = b3 ? s2[1] : s2[0];
        s3 = keep + shfl_xor4(send, 8);
    }
    s3 += shfl_xor4(s3, 4);

    if ((lane & 4) == 0) {
        int row = (lane >> 3) & 7;
        *(f32x4*)&tsp[wv][row][q * 4] = s3;
    }
    __syncthreads();

    // Sum the 4 wave partials into ts[8][16].
    if (t < 128) {
        int row = t >> 4, r = t & 15;
        ts[row][r] = tsp[0][row][r] + tsp[1][row][r]
                   + tsp[2][row][r] + tsp[3][row][r];
    }
    __syncthreads();

    // ---- Phase 2: R5-verified j-sweep. 4 j-tiles of 1024; w[16] in regs.
    const size_t obase = (size_t)row0 * NDIM;
    #pragma unroll 1
    for (int jt = 0; jt < 4; ++jt) {
        const int j0 = jt * 1024 + t * 4;
        f32x4 w[16];
        #pragma unroll
        for (int r = 0; r < 16; ++r)
            w[r] = *(const f32x4*)&w23[r * NDIM + j0];
        #pragma unroll 2
        for (int row = 0; row < 8; ++row) {
            const f32x4* trp = (const f32x4*)&ts[row][0];
            f32x4 t0 = trp[0], t1 = trp[1], t2 = trp[2], t3 = trp[3];
            f32x4 a = (f32x4)(0.f);
            a = fma4(t0.x, w[0],  a); a = fma4(t0.y, w[1],  a);
            a = fma4(t0.z, w[2],  a); a = fma4(t0.w, w[3],  a);
            a = fma4(t1.x, w[4],  a); a = fma4(t1.y, w[5],  a);
            a = fma4(t1.z, w[6],  a); a = fma4(t1.w, w[7],  a);
            a = fma4(t2.x, w[8],  a); a = fma4(t2.y, w[9],  a);
            a = fma4(t2.z, w[10], a); a = fma4(t2.w, w[11], a);
            a = fma4(t3.x, w[12], a); a = fma4(t3.y, w[13], a);
            a = fma4(t3.z, w[14], a); a = fma4(t3.w, w[15], a);
            __builtin_nontemporal_store(a,
                (f32x4*)&out[obase + (size_t)row * NDIM + j0]);
        }
    }
}

extern "C" void kernel_launch(void* const* d_in, const int* in_sizes, int n_in,
                              void* d_out, int out_size, void* d_ws, size_t ws_size,
                              hipStream_t stream) {
    const float* x  = (const float*)d_in[0];
    const float* c0 = (const float*)d_in[1];
    const float* c1 = (const float*)d_in[2];
    const float* c2 = (const float*)d_in[3];
    const float* c3 = (const float*)d_in[4];
    float* out = (float*)d_out;

    float* w01 = (float*)d_ws;
    float* w23 = w01 + 65536;

    tt_prep<<<512, 256, 0, stream>>>(c0, c1, c2, c3, w01, w23);
    tt_fused<<<1024, 256, 0, stream>>>(x, w01, w23, out);
}